// Round 7
// baseline (1784.844 us; speedup 1.0000x reference)
//
#include <hip/hip_runtime.h>

#define HH 32
#define LOG2E 1.44269504088896340736f

typedef float v2f __attribute__((ext_vector_type(2)));
typedef float v4f __attribute__((ext_vector_type(4)));

// DPP quad_perm controls: xor within the 4-lane gate group (gate = lane&3)
#define QP_XOR1 0xB1   // [1,0,3,2]
#define QP_XOR2 0x4E   // [2,3,0,1]
#define QP_XOR3 0x1B   // [3,2,1,0]
#define QPERM(v, ctrl) \
    __int_as_float(__builtin_amdgcn_update_dpp(0, __float_as_int(v), (ctrl), 0xF, 0xF, true))
// ds_swizzle BitMode xor-4: combine k-halves (half bit = lane bit 2)
#define SWZ_XOR4(v) __int_as_float(__builtin_amdgcn_ds_swizzle(__float_as_int(v), 0x101F))

__device__ __forceinline__ float hw_exp2(float x) {
    float r;
    asm("v_exp_f32 %0, %1" : "=v"(r) : "v"(x));   // guaranteed HW exp2
    return r;
}
__device__ __forceinline__ float sigm_e(float z, float escale) {
    // 1/(1 + exp2(z*escale)); sigmoid(z) when escale = -log2(e)
    return __builtin_amdgcn_rcpf(1.0f + hw_exp2(z * escale));
}
// guaranteed packed f32 FMA
__device__ __forceinline__ v2f pk_fma(v2f a, v2f b, v2f c) {
    v2f d;
    asm("v_pk_fma_f32 %0, %1, %2, %3" : "=v"(d) : "v"(a), "v"(b), "v"(c));
    return d;
}

__global__ __launch_bounds__(256, 4)
void lstm_seq_kernel(const float* __restrict__ input,
                     const float* __restrict__ W_ih1, const float* __restrict__ W_hh1,
                     const float* __restrict__ b_ih1, const float* __restrict__ b_hh1,
                     const float* __restrict__ W_ih2, const float* __restrict__ W_hh2,
                     const float* __restrict__ b_ih2, const float* __restrict__ b_hh2,
                     const float* __restrict__ W_lin, const float* __restrict__ b_lin,
                     float* __restrict__ out, int T, int total)
{
    const int b     = blockIdx.x;        // one block (4 waves) per batch element
    const int tid   = threadIdx.x;       // 0..255
    const int lane  = tid & 63;
    const int w     = tid >> 6;          // wave 0..3
    const int q     = lane & 3;          // gate: 0=i 1=f 2=g 3=o (quad_perm group)
    const int m     = lane >> 3;         // channel-within-wave 0..7
    const int ch    = (w << 3) | m;      // channel 0..31
    const int row   = (q << 5) | ch;     // gate row 0..127 (PyTorch i,f,g,o)
    const int kbase = lane & 4 ? 16 : 0; // this lane's k-half offset (half = bit2)

    __shared__ __align__(16) float h1buf[HH];
    __shared__ __align__(16) float h2buf[HH];

    // ---- resident weights: 16 floats (one k-half) per matrix = 64 VGPRs total ----
    v2f wh1v[8], wi2v[8], wh2v[8], wlv[8];
    {
        const v2f* p1 = (const v2f*)(W_hh1 + row * HH + kbase);
        const v2f* p2 = (const v2f*)(W_ih2 + row * HH + kbase);
        const v2f* p3 = (const v2f*)(W_hh2 + row * HH + kbase);
        const v2f* p4 = (const v2f*)(W_lin + kbase);
#pragma unroll
        for (int r = 0; r < 8; ++r) {
            wh1v[r] = p1[r]; wi2v[r] = p2[r]; wh2v[r] = p3[r]; wlv[r] = p4[r];
        }
    }
    const float wx   = W_ih1[row];
    const float b1   = b_ih1[row] + b_hh1[row];
    const float b2   = b_ih2[row] + b_hh2[row];
    const float blin = b_lin[0];

    // gate g (q==2) uses tanh = 2*sigmoid(2z)-1; i/f/o use sigmoid
    const bool  isg = (q == 2);
    const float es  = isg ? (-2.0f * LOG2E) : (-LOG2E);
    const float mm  = isg ? 2.0f : 1.0f;
    const float cc  = isg ? -1.0f : 0.0f;

    float c1 = 0.0f, c2 = 0.0f;      // valid on q==0 lanes only (others garbage)
    float ov = 0.0f;                 // previous output (all lanes, feedback)
    // carried HALF-partials (biases added post-combine to avoid double count):
    // a = Wh1[row, khalf]·h1(t-1),  e = Wh2[row, khalf]·h2(t-1) (+ Wi2·h1(t) in P1)
    v2f a01 = {0.f, 0.f}, a23 = {0.f, 0.f};
    v2f e01 = {0.f, 0.f}, e23 = {0.f, 0.f};

    const float* __restrict__ inp  = input + (size_t)b * T;
    float* __restrict__       outp = out   + (size_t)b * total;

    for (int t = 0; t < total; ++t) {
        float xin = inp[t < T ? t : (T - 1)];    // uniform load
        float x   = (t < T) ? xin : ov;          // autoregressive feedback in-reg

        // ---------- P0: z1 = x*wx + b1 + (combined carried partial) ----------
        float asum = (a01.x + a01.y) + (a23.x + a23.y);
        asum += SWZ_XOR4(asum);                          // combine k-halves
        float z1  = fmaf(x, wx, b1 + asum);
        float act = fmaf(mm, sigm_e(z1, es), cc);        // sig(i/f/o) | tanh(g)
        float vf  = QPERM(act, QP_XOR1);
        float vg  = QPERM(act, QP_XOR2);
        float vo  = QPERM(act, QP_XOR3);
        c1 = fmaf(vf, c1, act * vg);
        float h1 = vo * fmaf(2.0f, sigm_e(c1, -2.0f * LOG2E), -1.0f);  // tanh(c1)
        if ((lane & 7) == 0) h1buf[ch] = h1;             // q==0 && half==0
        __syncthreads();                                 // B1: h1 visible

        // ---------- P1: read own h1 k-half; z2 accumulate + next z1 carry ----------
        v2f hv[8];
        {
            const v4f* hp = (const v4f*)(h1buf + kbase);
#pragma unroll
            for (int r = 0; r < 4; ++r) {
                v4f v = hp[r];
                hv[2*r]   = __builtin_shufflevector(v, v, 0, 1);
                hv[2*r+1] = __builtin_shufflevector(v, v, 2, 3);
            }
        }
        a01 = (v2f){0.f, 0.f}; a23 = (v2f){0.f, 0.f};
#pragma unroll
        for (int r = 0; r < 8; r += 2) {
            e01 = pk_fma(hv[r],   wi2v[r],   e01);
            e23 = pk_fma(hv[r+1], wi2v[r+1], e23);
            a01 = pk_fma(hv[r],   wh1v[r],   a01);
            a23 = pk_fma(hv[r+1], wh1v[r+1], a23);
        }
        {
            float esum = (e01.x + e01.y) + (e23.x + e23.y);
            esum += SWZ_XOR4(esum);                      // combine k-halves
            float z2   = b2 + esum;
            float act2 = fmaf(mm, sigm_e(z2, es), cc);
            float vf2  = QPERM(act2, QP_XOR1);
            float vg2  = QPERM(act2, QP_XOR2);
            float vo2  = QPERM(act2, QP_XOR3);
            c2 = fmaf(vf2, c2, act2 * vg2);
            float h2 = vo2 * fmaf(2.0f, sigm_e(c2, -2.0f * LOG2E), -1.0f); // tanh(c2)
            if ((lane & 7) == 0) h2buf[ch] = h2;
        }
        __syncthreads();                                 // B2: h2 visible

        // ---------- P2: read own h2 k-half; next z2 carry + output dot ----------
        v2f gv[8];
        {
            const v4f* gp = (const v4f*)(h2buf + kbase);
#pragma unroll
            for (int r = 0; r < 4; ++r) {
                v4f v = gp[r];
                gv[2*r]   = __builtin_shufflevector(v, v, 0, 1);
                gv[2*r+1] = __builtin_shufflevector(v, v, 2, 3);
            }
        }
        e01 = (v2f){0.f, 0.f}; e23 = (v2f){0.f, 0.f};
        v2f o01 = {0.f, 0.f}, o23 = {0.f, 0.f};
#pragma unroll
        for (int r = 0; r < 8; r += 2) {
            e01 = pk_fma(gv[r],   wh2v[r],   e01);
            e23 = pk_fma(gv[r+1], wh2v[r+1], e23);
            o01 = pk_fma(gv[r],   wlv[r],    o01);
            o23 = pk_fma(gv[r+1], wlv[r+1],  o23);
        }
        float osum = (o01.x + o01.y) + (o23.x + o23.y);
        osum += SWZ_XOR4(osum);                          // combine k-halves
        ov = osum + blin;                                // all lanes hold out(t)
        if (tid == 0) outp[t] = ov;
    }
}

extern "C" void kernel_launch(void* const* d_in, const int* in_sizes, int n_in,
                              void* d_out, int out_size, void* d_ws, size_t ws_size,
                              hipStream_t stream) {
    const int B = 1024;                 // fixed by the source module
    const int T = in_sizes[0] / B;      // 999
    const int total = out_size / B;     // T + future = 1999

    lstm_seq_kernel<<<dim3(B), dim3(256), 0, stream>>>(
        (const float*)d_in[0],
        (const float*)d_in[1], (const float*)d_in[2],
        (const float*)d_in[3], (const float*)d_in[4],
        (const float*)d_in[5], (const float*)d_in[6],
        (const float*)d_in[7], (const float*)d_in[8],
        (const float*)d_in[9], (const float*)d_in[10],
        (float*)d_out, T, total);
}

// Round 8
// 1322.991 us; speedup vs baseline: 1.3491x; 1.3491x over previous
//
#include <hip/hip_runtime.h>

#define HH 32
#define LOG2E 1.44269504088896340736f

typedef float v2f __attribute__((ext_vector_type(2)));

// DPP quad_perm controls: xor within the 4-lane gate group (q = lane&3)
#define QP_XOR1 0xB1   // [1,0,3,2]
#define QP_XOR2 0x4E   // [2,3,0,1]
#define QP_XOR3 0x1B   // [3,2,1,0]
#define QPERM(v, ctrl) \
    __int_as_float(__builtin_amdgcn_update_dpp(0, __float_as_int(v), (ctrl), 0xF, 0xF, true))

__device__ __forceinline__ float hw_exp2(float x) {
    float r;
    asm("v_exp_f32 %0, %1" : "=v"(r) : "v"(x));   // guaranteed HW exp2
    return r;
}
__device__ __forceinline__ float sigm_e(float z, float escale) {
    // 1/(1 + exp2(z*escale)); sigmoid(z) when escale = -log2(e)
    return __builtin_amdgcn_rcpf(1.0f + hw_exp2(z * escale));
}
// packed f32 FMA via compiler (lowers to v_pk_fma_f32; allocator may fold ACC operands)
__device__ __forceinline__ v2f pk_fma(v2f a, v2f b, v2f c) {
    return __builtin_elementwise_fma(a, b, c);
}

__global__ __launch_bounds__(128, 2)
void lstm_seq_kernel(const float* __restrict__ input,
                     const float* __restrict__ W_ih1, const float* __restrict__ W_hh1,
                     const float* __restrict__ b_ih1, const float* __restrict__ b_hh1,
                     const float* __restrict__ W_ih2, const float* __restrict__ W_hh2,
                     const float* __restrict__ b_ih2, const float* __restrict__ b_hh2,
                     const float* __restrict__ W_lin, const float* __restrict__ b_lin,
                     float* __restrict__ out, int T, int total)
{
    const int b    = blockIdx.x;     // one block (2 waves) per batch element
    const int tid  = threadIdx.x;    // 0..127
    const int w    = tid >> 6;       // wave 0/1
    const int lane = tid & 63;
    const int q    = lane & 3;       // gate: 0=i 1=f 2=g 3=o (quad_perm neighbors)
    const int m    = lane >> 2;      // channel-within-wave 0..15
    const int j    = (w << 4) | m;   // channel 0..31
    const int row  = (q << 5) | j;   // gate row 0..127 (PyTorch i,f,g,o blocks)

    __shared__ __align__(16) float h1buf[HH];
    __shared__ __align__(16) float h2buf[HH];

    // ---- resident weights as float2: 4 arrays x 16 pairs = 128 floats/lane ----
    v2f wh1v[16], wi2v[16], wh2v[16], wlv[16];
    {
        const v2f* p1 = (const v2f*)(W_hh1 + row * HH);
        const v2f* p2 = (const v2f*)(W_ih2 + row * HH);
        const v2f* p3 = (const v2f*)(W_hh2 + row * HH);
        const v2f* p4 = (const v2f*)(W_lin);            // replicated on all lanes
#pragma unroll
        for (int r = 0; r < 16; ++r) {
            wh1v[r] = p1[r]; wi2v[r] = p2[r]; wh2v[r] = p3[r]; wlv[r] = p4[r];
        }
    }
    const float wx   = W_ih1[row];
    const float b1   = b_ih1[row] + b_hh1[row];
    const float b2   = b_ih2[row] + b_hh2[row];
    const float blin = b_lin[0];

    // gate g (q==2) uses tanh = 2*sigmoid(2z)-1; i/f/o use sigmoid
    const bool  isg = (q == 2);
    const float es  = isg ? (-2.0f * LOG2E) : (-LOG2E);
    const float mm  = isg ? 2.0f : 1.0f;
    const float cc  = isg ? -1.0f : 0.0f;

    float c1 = 0.0f, c2 = 0.0f;      // valid on q==0 lanes (others harmless garbage)
    float ov = 0.0f;                 // previous output (all lanes, feedback)
    // carried partials: a = b1 + Wh1*h1(t-1), e = b2 + Wh2*h2(t-1), as packed pairs
    v2f a01 = {b1, 0.0f}, a23 = {0.0f, 0.0f};
    v2f e01 = {b2, 0.0f}, e23 = {0.0f, 0.0f};

    const float* __restrict__ inp  = input + (size_t)b * T;
    float* __restrict__       outp = out   + (size_t)b * total;

    for (int t = 0; t < total; ++t) {
        float xin = inp[t < T ? t : (T - 1)];    // uniform load
        float x   = (t < T) ? xin : ov;          // autoregressive feedback in-reg

        // ---------- P0: z1 from carried partial (short critical path) ----------
        float z1  = fmaf(x, wx, (a01.x + a01.y) + (a23.x + a23.y));
        float act = fmaf(mm, sigm_e(z1, es), cc);       // sig(i/f/o) | tanh(g)
        float vf  = QPERM(act, QP_XOR1);                // q=0 lane: gate f
        float vg  = QPERM(act, QP_XOR2);                // q=0 lane: gate g
        float vo  = QPERM(act, QP_XOR3);                // q=0 lane: gate o
        c1 = fmaf(vf, c1, act * vg);
        float h1 = vo * fmaf(2.0f, sigm_e(c1, -2.0f * LOG2E), -1.0f);  // tanh(c1)
        if (q == 0) h1buf[j] = h1;

        __syncthreads();                                 // B1: h1 visible

        // ---------- P1: one h1 read feeds BOTH z2 and next-step's z1 partial ----
        v2f hv[16];
#pragma unroll
        for (int r = 0; r < 8; ++r) {
            float4 v = ((const float4*)h1buf)[r];
            hv[2*r]   = (v2f){v.x, v.y};
            hv[2*r+1] = (v2f){v.z, v.w};
        }
        a01 = (v2f){b1, 0.0f}; a23 = (v2f){0.0f, 0.0f};
#pragma unroll
        for (int r = 0; r < 16; r += 2) {
            e01 = pk_fma(hv[r],   wi2v[r],   e01);
            e23 = pk_fma(hv[r+1], wi2v[r+1], e23);
            a01 = pk_fma(hv[r],   wh1v[r],   a01);
            a23 = pk_fma(hv[r+1], wh1v[r+1], a23);
        }
        {
            float z2   = (e01.x + e01.y) + (e23.x + e23.y);
            float act2 = fmaf(mm, sigm_e(z2, es), cc);
            float vf2  = QPERM(act2, QP_XOR1);
            float vg2  = QPERM(act2, QP_XOR2);
            float vo2  = QPERM(act2, QP_XOR3);
            c2 = fmaf(vf2, c2, act2 * vg2);
            float h2 = vo2 * fmaf(2.0f, sigm_e(c2, -2.0f * LOG2E), -1.0f); // tanh(c2)
            if (q == 0) h2buf[j] = h2;
        }

        __syncthreads();                                 // B2: h2 visible

        // ---------- P2: one h2 read feeds BOTH next z2 partial and the output ----
        v2f gv[16];
#pragma unroll
        for (int r = 0; r < 8; ++r) {
            float4 v = ((const float4*)h2buf)[r];
            gv[2*r]   = (v2f){v.x, v.y};
            gv[2*r+1] = (v2f){v.z, v.w};
        }
        e01 = (v2f){b2, 0.0f}; e23 = (v2f){0.0f, 0.0f};
        v2f o01 = {blin, 0.0f}, o23 = {0.0f, 0.0f};
#pragma unroll
        for (int r = 0; r < 16; r += 2) {
            e01 = pk_fma(gv[r],   wh2v[r],   e01);
            e23 = pk_fma(gv[r+1], wh2v[r+1], e23);
            o01 = pk_fma(gv[r],   wlv[r],    o01);
            o23 = pk_fma(gv[r+1], wlv[r+1],  o23);
        }
        ov = (o01.x + o01.y) + (o23.x + o23.y);          // all lanes, redundantly
        if (tid == 0) outp[t] = ov;
    }
}

extern "C" void kernel_launch(void* const* d_in, const int* in_sizes, int n_in,
                              void* d_out, int out_size, void* d_ws, size_t ws_size,
                              hipStream_t stream) {
    const int B = 1024;                 // fixed by the source module
    const int T = in_sizes[0] / B;      // 999
    const int total = out_size / B;     // T + future = 1999

    lstm_seq_kernel<<<dim3(B), dim3(128), 0, stream>>>(
        (const float*)d_in[0],
        (const float*)d_in[1], (const float*)d_in[2],
        (const float*)d_in[3], (const float*)d_in[4],
        (const float*)d_in[5], (const float*)d_in[6],
        (const float*)d_in[7], (const float*)d_in[8],
        (const float*)d_in[9], (const float*)d_in[10],
        (float*)d_out, T, total);
}

// Round 9
// 1270.762 us; speedup vs baseline: 1.4045x; 1.0411x over previous
//
#include <hip/hip_runtime.h>

#define HH 32
#define LOG2E 1.44269504088896340736f

typedef float v2f __attribute__((ext_vector_type(2)));

// DPP quad_perm controls: xor within the 4-lane gate group (q = lane&3)
#define QP_XOR1 0xB1   // [1,0,3,2]
#define QP_XOR2 0x4E   // [2,3,0,1]
#define QP_XOR3 0x1B   // [3,2,1,0]
#define QPERM(v, ctrl) \
    __int_as_float(__builtin_amdgcn_update_dpp(0, __float_as_int(v), (ctrl), 0xF, 0xF, true))

__device__ __forceinline__ float hw_exp2(float x) {
    float r;
    asm("v_exp_f32 %0, %1" : "=v"(r) : "v"(x));   // guaranteed HW exp2
    return r;
}
__device__ __forceinline__ float sigm_e(float z, float escale) {
    // 1/(1 + exp2(z*escale)); sigmoid(z) when escale = -log2(e)
    return __builtin_amdgcn_rcpf(1.0f + hw_exp2(z * escale));
}
// packed f32 FMA via compiler (lowers to v_pk_fma_f32; ACC operands fold freely)
__device__ __forceinline__ v2f pk_fma(v2f a, v2f b, v2f c) {
    return __builtin_elementwise_fma(a, b, c);
}

__global__ __launch_bounds__(128, 2)
void lstm_seq_kernel(const float* __restrict__ input,
                     const float* __restrict__ W_ih1, const float* __restrict__ W_hh1,
                     const float* __restrict__ b_ih1, const float* __restrict__ b_hh1,
                     const float* __restrict__ W_ih2, const float* __restrict__ W_hh2,
                     const float* __restrict__ b_ih2, const float* __restrict__ b_hh2,
                     const float* __restrict__ W_lin, const float* __restrict__ b_lin,
                     float* __restrict__ out, int T, int total)
{
    const int b    = blockIdx.x;     // one block (2 waves) per batch element
    const int tid  = threadIdx.x;    // 0..127
    const int w    = tid >> 6;       // wave 0/1
    const int lane = tid & 63;
    const int q    = lane & 3;       // gate: 0=i 1=f 2=g 3=o (quad_perm neighbors)
    const int m    = lane >> 2;      // channel-within-wave 0..15
    const int j    = (w << 4) | m;   // channel 0..31
    const int row  = (q << 5) | j;   // gate row 0..127 (PyTorch i,f,g,o blocks)

    __shared__ __align__(16) float h1buf[HH];
    __shared__ __align__(16) float h2buf[HH];

    // ---- resident weights as float2: 4 arrays x 16 pairs = 128 floats/lane ----
    v2f wh1v[16], wi2v[16], wh2v[16], wlv[16];
    {
        const v2f* p1 = (const v2f*)(W_hh1 + row * HH);
        const v2f* p2 = (const v2f*)(W_ih2 + row * HH);
        const v2f* p3 = (const v2f*)(W_hh2 + row * HH);
        const v2f* p4 = (const v2f*)(W_lin);            // replicated on all lanes
#pragma unroll
        for (int r = 0; r < 16; ++r) {
            wh1v[r] = p1[r]; wi2v[r] = p2[r]; wh2v[r] = p3[r]; wlv[r] = p4[r];
        }
    }
    const float wx   = W_ih1[row];
    const float b1   = b_ih1[row] + b_hh1[row];
    const float b2   = b_ih2[row] + b_hh2[row];
    const float blin = b_lin[0];

    // gate g (q==2) uses tanh = 2*sigmoid(2z)-1; i/f/o use sigmoid
    const bool  isg = (q == 2);
    const float es  = isg ? (-2.0f * LOG2E) : (-LOG2E);
    const float mm  = isg ? 2.0f : 1.0f;
    const float cc  = isg ? -1.0f : 0.0f;

    float c1 = 0.0f, c2 = 0.0f;      // valid on q==0 lanes (others harmless garbage)
    // pipelined register state:
    v2f hv[16];                      // h1(t) broadcast (read in P1, reused post-B2)
    v2f gv[16];                      // h2(t-1) broadcast (read in P2, reused next P1)
#pragma unroll
    for (int r = 0; r < 16; ++r) { hv[r] = (v2f){0.f, 0.f}; gv[r] = (v2f){0.f, 0.f}; }
    // a-carry = b1 + Wh1*h1(t-1): consumed at P0, produced post-B2
    v2f a01 = {b1, 0.0f}, a23 = {0.0f, 0.0f};

    const float* __restrict__ inp  = input + (size_t)b * T;
    float* __restrict__       outp = out   + (size_t)b * total;
    float x = inp[0];

    for (int t = 0; t < total; ++t) {
        // ---------- P0: z1 from carried partial (short critical path) ----------
        float z1  = fmaf(x, wx, (a01.x + a01.y) + (a23.x + a23.y));
        float act = fmaf(mm, sigm_e(z1, es), cc);       // sig(i/f/o) | tanh(g)
        float vf  = QPERM(act, QP_XOR1);                // q=0 lane: gate f
        float vg  = QPERM(act, QP_XOR2);                // q=0 lane: gate g
        float vo  = QPERM(act, QP_XOR3);                // q=0 lane: gate o
        c1 = fmaf(vf, c1, act * vg);
        float h1 = vo * fmaf(2.0f, sigm_e(c1, -2.0f * LOG2E), -1.0f);  // tanh(c1)
        if (q == 0) h1buf[j] = h1;

        __syncthreads();                                 // B1: h1 visible

        // ---------- P1: issue h1 reads; e-carry on gv fills the latency shadow ----
        float4 hraw[8];
#pragma unroll
        for (int r = 0; r < 8; ++r) hraw[r] = ((const float4*)h1buf)[r];

        v2f e01 = {b2, 0.0f}, e23 = {0.0f, 0.0f};
#pragma unroll
        for (int r = 0; r < 16; r += 2) {                // independent of hraw
            e01 = pk_fma(gv[r],   wh2v[r],   e01);
            e23 = pk_fma(gv[r+1], wh2v[r+1], e23);
        }
#pragma unroll
        for (int r = 0; r < 8; ++r) {
            hv[2*r]   = (v2f){hraw[r].x, hraw[r].y};
            hv[2*r+1] = (v2f){hraw[r].z, hraw[r].w};
        }
#pragma unroll
        for (int r = 0; r < 16; r += 2) {                // dependent on h1 read
            e01 = pk_fma(hv[r],   wi2v[r],   e01);
            e23 = pk_fma(hv[r+1], wi2v[r+1], e23);
        }
        {
            float z2   = (e01.x + e01.y) + (e23.x + e23.y);
            float act2 = fmaf(mm, sigm_e(z2, es), cc);
            float vf2  = QPERM(act2, QP_XOR1);
            float vg2  = QPERM(act2, QP_XOR2);
            float vo2  = QPERM(act2, QP_XOR3);
            c2 = fmaf(vf2, c2, act2 * vg2);
            float h2 = vo2 * fmaf(2.0f, sigm_e(c2, -2.0f * LOG2E), -1.0f); // tanh(c2)
            if (q == 0) h2buf[j] = h2;
        }

        __syncthreads();                                 // B2: h2 visible

        // ---------- P2: issue h2 reads; a-carry on hv fills the latency shadow ----
        float4 graw[8];
#pragma unroll
        for (int r = 0; r < 8; ++r) graw[r] = ((const float4*)h2buf)[r];

        a01 = (v2f){b1, 0.0f}; a23 = (v2f){0.0f, 0.0f};
#pragma unroll
        for (int r = 0; r < 16; r += 2) {                // independent of graw
            a01 = pk_fma(hv[r],   wh1v[r],   a01);
            a23 = pk_fma(hv[r+1], wh1v[r+1], a23);
        }
#pragma unroll
        for (int r = 0; r < 8; ++r) {
            gv[2*r]   = (v2f){graw[r].x, graw[r].y};
            gv[2*r+1] = (v2f){graw[r].z, graw[r].w};
        }
        v2f o01 = {blin, 0.0f}, o23 = {0.0f, 0.0f};
#pragma unroll
        for (int r = 0; r < 16; r += 2) {                // dependent on h2 read
            o01 = pk_fma(gv[r],   wlv[r],    o01);
            o23 = pk_fma(gv[r+1], wlv[r+1],  o23);
        }
        float ov = (o01.x + o01.y) + (o23.x + o23.y);    // all lanes, redundantly
        if (tid == 0) outp[t] = ov;

        int tn = t + 1;
        float xin = inp[tn < T ? tn : (T - 1)];          // uniform load
        x = (tn < T) ? xin : ov;                         // feedback only in AR phase
    }
}

extern "C" void kernel_launch(void* const* d_in, const int* in_sizes, int n_in,
                              void* d_out, int out_size, void* d_ws, size_t ws_size,
                              hipStream_t stream) {
    const int B = 1024;                 // fixed by the source module
    const int T = in_sizes[0] / B;      // 999
    const int total = out_size / B;     // T + future = 1999

    lstm_seq_kernel<<<dim3(B), dim3(128), 0, stream>>>(
        (const float*)d_in[0],
        (const float*)d_in[1], (const float*)d_in[2],
        (const float*)d_in[3], (const float*)d_in[4],
        (const float*)d_in[5], (const float*)d_in[6],
        (const float*)d_in[7], (const float*)d_in[8],
        (const float*)d_in[9], (const float*)d_in[10],
        (float*)d_out, T, total);
}